// Round 5
// baseline (4311.717 us; speedup 1.0000x reference)
//
#include <hip/hip_runtime.h>
#include <hip/hip_bf16.h>

// Persistent bidirectional LSTM for MI355X. B=32, T=512, H=512.
//
// R7: xg hoist -> 2952 us (lstm_rec 2690 = 5.25 us/step). FETCH 332 MB shows
// ~120 MB h-ring readback from HBM/L3: the agent-scope (sc1) exchange
// round-trips the DIE-LEVEL coherence point; every hop is ~1-2 kcy.
// R8 (failed to bench): XCD-local exchange, but two novel inline-asm
// constructs (s_getreg syntax; pointer-in-"v"-constraint global_load) are
// the prime suspects for the failure.
// R9 = R8 with zero new inline asm:
//   - XCC id via __builtin_amdgcn_s_getreg(hwreg(20,0,32) encoding).
//   - ALL polls are the proven agent-scope relaxed atomic loads (L1-bypass).
//   - fast mode differs ONLY in store scope: h-publish + flag-publish are
//     WORKGROUP-scope (plain write-back stores that stop at the XCD L2;
//     CDNA L1 is write-through so same-XCD L1-bypassing readers see them).
//     slow mode = R7 agent-scope protocol (correct under any placement).
//   - 768 WGs self-place: XCD0 claims fwd roles, XCD1 bwd via agent ticket;
//     100us timeout lets anyone steal unfilled roles (no deadlock); one-time
//     co-location verification gates the fast protocol per direction.

#define HDIM 512
#define TDIM 512
#define BDIM 32
#define NWG  64     // workgroups per direction (recurrence)
#define NTHR 256
#define GRID_REC 768 // oversubscribed for XCD self-placement
#define CSTRIDE 16  // ints per counter slot (fallback modes 1/2)
#define FLAGN 64    // one flag word per producer WG
#define SLOTS (TDIM + 1)

typedef float f32x4 __attribute__((ext_vector_type(4)));
typedef _Float16 half8 __attribute__((ext_vector_type(8)));
typedef unsigned long long u64x2 __attribute__((ext_vector_type(2)));

#define SLICE_INTS (BDIM * HDIM / 2)   // 8192 ints = 32 KB per (step,dir) slice
#define FLAG_INTS (2 * SLOTS * FLAGN)  // 65664
#define CLAIM_OFF FLAG_INTS            // 2 ints (padded to 16)
#define XCCREC_OFF (FLAG_INTS + 16)    // 2*NWG ints
#define SYNC_INTS (FLAG_INTS + 16 + 2 * NWG)

__device__ __forceinline__ float sigm(float x) { return 1.f / (1.f + __expf(-x)); }
__device__ __forceinline__ float tanh_f(float x) { return 1.f - 2.f / (__expf(2.f * x) + 1.f); }

__device__ __forceinline__ void st_scoped(int* p, int v, bool fast) {
  if (fast) __hip_atomic_store(p, v, __ATOMIC_RELAXED, __HIP_MEMORY_SCOPE_WORKGROUP);
  else      __hip_atomic_store(p, v, __ATOMIC_RELAXED, __HIP_MEMORY_SCOPE_AGENT);
}

__global__ void init_ws_kernel(int* __restrict__ sync, int* __restrict__ hbuf_i,
                               int nzero) {
  int i = blockIdx.x * blockDim.x + threadIdx.x;
  int n = blockDim.x * gridDim.x;
  for (int j = i; j < nzero; j += n)
    __hip_atomic_store(sync + j, 0, __ATOMIC_RELAXED, __HIP_MEMORY_SCOPE_AGENT);
  for (int j = i; j < 2 * SLICE_INTS; j += n)   // slice 0 (h0 = 0), both dirs
    __hip_atomic_store(hbuf_i + j, 0, __ATOMIC_RELAXED, __HIP_MEMORY_SCOPE_AGENT);
}

// ---------------------------------------------------------------------------
// xg precompute GEMM (unchanged from R7): xg[d][t][b][2048] fp16 =
// x @ Wih^T + bih + bhh. 128x128 tile, K=512.
// ---------------------------------------------------------------------------
__global__ __launch_bounds__(NTHR, 1)
void xg_gemm(const float* __restrict__ x,
             const float* __restrict__ WihF, const float* __restrict__ bihF,
             const float* __restrict__ bhhF,
             const float* __restrict__ WihB, const float* __restrict__ bihB,
             const float* __restrict__ bhhB,
             _Float16* __restrict__ xg) {
  const int blk = blockIdx.x;
  const int mb = blk & 127;
  const int ndb = blk >> 7;
  const int d = ndb >> 4;
  const int nb = ndb & 15;
  const float* Wih = d ? WihB : WihF;
  const float* bih = d ? bihB : bihF;
  const float* bhh = d ? bhhB : bhhF;
  const int mbase = mb * 128;
  const int nbase = nb * 128;

  __shared__ _Float16 As[128][40];
  __shared__ _Float16 Bs[128][40];

  const int tid = threadIdx.x;
  const int lane = tid & 63;
  const int wv = tid >> 6;
  const int wm = wv >> 1, wn = wv & 1;
  const int ln = lane & 15, quad = lane >> 4;

  f32x4 acc[4][4];
#pragma unroll
  for (int i = 0; i < 4; ++i)
#pragma unroll
    for (int j = 0; j < 4; ++j) acc[i][j] = (f32x4){0.f, 0.f, 0.f, 0.f};

  const int srow = tid >> 1, shalf = tid & 1;

  for (int kt = 0; kt < 16; ++kt) {
    const float* pa = x + (size_t)(mbase + srow) * 512 + kt * 32 + shalf * 16;
    const float* pb = Wih + (size_t)(nbase + srow) * 512 + kt * 32 + shalf * 16;
    f32x4 a0 = ((const f32x4*)pa)[0], a1 = ((const f32x4*)pa)[1];
    f32x4 a2 = ((const f32x4*)pa)[2], a3 = ((const f32x4*)pa)[3];
    f32x4 b0 = ((const f32x4*)pb)[0], b1 = ((const f32x4*)pb)[1];
    f32x4 b2 = ((const f32x4*)pb)[2], b3 = ((const f32x4*)pb)[3];
    half8 alo, ahi, blo, bhi;
#pragma unroll
    for (int j = 0; j < 4; ++j) {
      alo[j] = (_Float16)a0[j]; alo[4 + j] = (_Float16)a1[j];
      ahi[j] = (_Float16)a2[j]; ahi[4 + j] = (_Float16)a3[j];
      blo[j] = (_Float16)b0[j]; blo[4 + j] = (_Float16)b1[j];
      bhi[j] = (_Float16)b2[j]; bhi[4 + j] = (_Float16)b3[j];
    }
    __syncthreads();
    *(half8*)&As[srow][shalf * 16] = alo;
    *(half8*)&As[srow][shalf * 16 + 8] = ahi;
    *(half8*)&Bs[srow][shalf * 16] = blo;
    *(half8*)&Bs[srow][shalf * 16 + 8] = bhi;
    __syncthreads();

    half8 af[4], bf[4];
#pragma unroll
    for (int i = 0; i < 4; ++i) {
      af[i] = *(const half8*)&As[wm * 64 + i * 16 + ln][quad * 8];
      bf[i] = *(const half8*)&Bs[wn * 64 + i * 16 + ln][quad * 8];
    }
#pragma unroll
    for (int i = 0; i < 4; ++i)
#pragma unroll
      for (int j = 0; j < 4; ++j)
        acc[i][j] = __builtin_amdgcn_mfma_f32_16x16x32_f16(af[i], bf[j], acc[i][j], 0, 0, 0);
  }

  _Float16* xgd = xg + (size_t)d * 512 * 32 * 2048;
#pragma unroll
  for (int j = 0; j < 4; ++j) {
    const int n = nbase + wn * 64 + j * 16 + ln;
    const float bs = bih[n] + bhh[n];
#pragma unroll
    for (int i = 0; i < 4; ++i) {
#pragma unroll
      for (int r = 0; r < 4; ++r) {
        const int m = mbase + wm * 64 + i * 16 + quad * 4 + r;
        const int t = m & 511;
        const int b = m >> 9;
        xgd[(((size_t)t * 32 + b) * 2048) + n] = (_Float16)(acc[i][j][r] + bs);
      }
    }
  }
}

// ---------------------------------------------------------------------------
// Recurrence kernel: XCD self-placement + dual-protocol exchange.
// ---------------------------------------------------------------------------
__global__ __launch_bounds__(NTHR, 1)
void lstm_rec(const float* __restrict__ WhhF, const float* __restrict__ WhhB,
              float* __restrict__ out, int* __restrict__ sync,
              int* __restrict__ hbuf, const _Float16* __restrict__ xg) {
  const int tid = threadIdx.x;
  const int lane = tid & 63;
  const int wv = tid >> 6;

  // ---- claim a role, preferring the XCD that owns this direction ----
  __shared__ int srole[2];
  __shared__ int sfast;
  if (tid == 0) {
    // hwreg(HW_REG_XCC_ID=20, offset=0, size=32): imm = (31<<11) | 20
    int xcc = __builtin_amdgcn_s_getreg((31 << 11) | 20) & 7;
    int* claim = sync + CLAIM_OFF;
    int dir = -1, role = -1;
    if (xcc < 2) {
      int t = __hip_atomic_fetch_add(&claim[xcc], 1, __ATOMIC_RELAXED,
                                     __HIP_MEMORY_SCOPE_AGENT);
      if (t < NWG) { dir = xcc; role = t; }
    }
    if (role < 0) {
      const unsigned long long t0 = __builtin_amdgcn_s_memrealtime();
      for (;;) {
        int c0 = __hip_atomic_load(&claim[0], __ATOMIC_RELAXED, __HIP_MEMORY_SCOPE_AGENT);
        int c1 = __hip_atomic_load(&claim[1], __ATOMIC_RELAXED, __HIP_MEMORY_SCOPE_AGENT);
        if (c0 >= NWG && c1 >= NWG) break;          // all roles claimed
        if (__builtin_amdgcn_s_memrealtime() - t0 > 10000) {  // ~100 us: steal
          for (int dd = 0; dd < 2 && role < 0; ++dd) {
            int t = __hip_atomic_fetch_add(&claim[dd], 1, __ATOMIC_RELAXED,
                                           __HIP_MEMORY_SCOPE_AGENT);
            if (t < NWG) { dir = dd; role = t; }
          }
          break;
        }
        __builtin_amdgcn_s_sleep(8);
      }
    }
    srole[0] = dir; srole[1] = role;
    if (role >= 0)
      __hip_atomic_store(sync + XCCREC_OFF + dir * NWG + role, xcc + 1,
                         __ATOMIC_RELAXED, __HIP_MEMORY_SCOPE_AGENT);
  }
  __syncthreads();
  const int d = srole[0];
  const int w = srole[1];
  if (d < 0) return;

  // ---- one-time co-location check: all 64 workers of dir d on XCD d? ----
  if (wv == 0) {
    const int* px = sync + XCCREC_OFF + d * NWG + lane;
    int v;
    while ((v = __hip_atomic_load(px, __ATOMIC_RELAXED, __HIP_MEMORY_SCOPE_AGENT)) == 0) {}
    const unsigned long long m = __ballot(v == d + 1);
    if (tid == 0) sfast = (m == ~0ull) ? 1 : 0;
  }
  __syncthreads();
  const bool fast = (sfast != 0);  // uniform across the direction

  const int nt = wv & 1;             // jj-half
  const int mt = wv >> 1;            // batch half
  const float* Whh = d ? WhhB : WhhF;

  const int nn = lane & 15;
  const int quad = lane >> 4;
  const int gg = nn & 3;             // gate 0..3 (i,f,g,o) -- interleaved
  const int jj = nt * 4 + (nn >> 2);
  const int gc = gg * HDIM + w * 8 + jj;
  const int b0 = mt * 16 + quad * 4;

  half8 whhf[16];
#pragma unroll
  for (int kbi = 0; kbi < 16; ++kbi) {
    const int k0 = kbi * 32 + quad * 8;
    const f32x4* ph = (const f32x4*)(Whh + (size_t)gc * HDIM + k0);
    f32x4 h0 = ph[0], h1 = ph[1];
    half8 b;
#pragma unroll
    for (int j = 0; j < 4; ++j) { b[j] = (_Float16)h0[j]; b[4 + j] = (_Float16)h1[j]; }
    whhf[kbi] = b;
  }

  const _Float16* xgd = xg + (size_t)d * 512 * 32 * 2048;
  const int tstep = d ? -1 : 1;
  int tx = d ? (TDIM - 1) : 0;

  _Float16 xh0, xh1, xh2, xh3;
  {
    const _Float16* xp = xgd + ((size_t)tx * 32 + b0) * 2048 + gc;
    xh0 = xp[0]; xh1 = xp[2048]; xh2 = xp[4096]; xh3 = xp[6144];
  }

  float c0 = 0.f, c1 = 0.f, c2 = 0.f, c3 = 0.f;

  for (int s = 0; s < TDIM; ++s, tx += tstep) {
    f32x4 acc = {(float)xh0, (float)xh1, (float)xh2, (float)xh3};

    // ---- wait for slice s: agent relaxed load (L1-bypass), proven ----
    if (s > 0) {
      if (wv == 0) {
        const int* pf = sync + (size_t)(d * SLOTS + s) * FLAGN + lane;
        while (__hip_atomic_load(pf, __ATOMIC_RELAXED, __HIP_MEMORY_SCOPE_AGENT) == 0) {}
      }
      __syncthreads();  // broadcast + compiler barrier
    }

    // ---- h-phase: 16 MFMAs, cached ring loads (fresh addresses) ----
    const _Float16* hb = (const _Float16*)(hbuf + ((size_t)s * 2 + d) * SLICE_INTS);
#pragma unroll
    for (int kbi = 0; kbi < 16; ++kbi) {
      const int k0 = kbi * 32 + quad * 8;
      half8 a = *(const half8*)(hb + (mt * 16 + nn) * HDIM + k0);
      acc = __builtin_amdgcn_mfma_f32_16x16x32_f16(a, whhf[kbi], acc, 0, 0, 0);
    }

    // ---- intra-wave cell update ----
    float h0f, h1f, h2f, h3f;
    {
      float g0, g1, g2, g3, t1, t2;
#define CELL(R, CR, HF)                                                     \
      g0 = acc[R];                                                          \
      t1 = __shfl_xor(acc[R], 1);                                           \
      t2 = __shfl_xor(acc[R], 2);                                           \
      g3 = __shfl_xor(t1, 2);                                               \
      g1 = t1; g2 = t2;                                                     \
      {                                                                     \
        const float iv = sigm(g0), fv = sigm(g1);                           \
        const float gv = tanh_f(g2), ov = sigm(g3);                         \
        CR = fv * CR + iv * gv;                                             \
        HF = ov * tanh_f(CR);                                               \
      }
      CELL(0, c0, h0f) CELL(1, c1, h1f) CELL(2, c2, h2f) CELL(3, c3, h3f)
#undef CELL
    }

    // ---- publish h (fast: workgroup-scope write-back, stops at XCD L2) ----
    const float hn0 = __shfl_xor(h0f, 4);
    const float hn1 = __shfl_xor(h1f, 4);
    const float hn2 = __shfl_xor(h2f, 4);
    const float hn3 = __shfl_xor(h3f, 4);
    {
      int* hw = hbuf + ((size_t)(s + 1) * 2 + d) * SLICE_INTS;
      if ((nn & 7) == 0) {
        const int colint = w * 4 + nt * 2 + (nn >> 3);
#define PUB(R, HF, HN)                                                       \
        {                                                                    \
          const unsigned lo = (unsigned)__builtin_bit_cast(unsigned short, (_Float16)(HF)); \
          const unsigned hi = (unsigned)__builtin_bit_cast(unsigned short, (_Float16)(HN)); \
          st_scoped(hw + (b0 + R) * (HDIM / 2) + colint,                     \
                    (int)(lo | (hi << 16)), fast);                           \
        }
        PUB(0, h0f, hn0) PUB(1, h1f, hn1) PUB(2, h2f, hn2) PUB(3, h3f, hn3)
#undef PUB
      }
    }

    // __syncthreads drains vmcnt(0) per wave: h stores acked (local L2 in
    // fast mode, die coherence point in agent mode) before the flag store.
    __syncthreads();
    if (tid == 0)
      st_scoped(sync + (size_t)(d * SLOTS + s + 1) * FLAGN + w, 1, fast);

    // ---- out store (orderless) + xg prefetch for next step ----
    if (gg == 0) {
      out[((size_t)(b0 + 0) * TDIM + tx) * (2 * HDIM) + d * HDIM + w * 8 + jj] = h0f;
      out[((size_t)(b0 + 1) * TDIM + tx) * (2 * HDIM) + d * HDIM + w * 8 + jj] = h1f;
      out[((size_t)(b0 + 2) * TDIM + tx) * (2 * HDIM) + d * HDIM + w * 8 + jj] = h2f;
      out[((size_t)(b0 + 3) * TDIM + tx) * (2 * HDIM) + d * HDIM + w * 8 + jj] = h3f;
    }
    if (s + 1 < TDIM) {
      const _Float16* xp = xgd + ((size_t)(tx + tstep) * 32 + b0) * 2048 + gc;
      xh0 = xp[0]; xh1 = xp[2048]; xh2 = xp[4096]; xh3 = xp[6144];
    }
  }
}

// ---------------------------------------------------------------------------
// Fallback: R5 kernel verbatim (flag ring / counter ring / dbuf).
// ---------------------------------------------------------------------------
template <int MODE>
__global__ __launch_bounds__(NTHR, 1)
void lstm_kernel(const float* __restrict__ x,
                 const float* __restrict__ WihF, const float* __restrict__ WhhF,
                 const float* __restrict__ bihF, const float* __restrict__ bhhF,
                 const float* __restrict__ WihB, const float* __restrict__ WhhB,
                 const float* __restrict__ bihB, const float* __restrict__ bhhB,
                 float* __restrict__ out,
                 int* __restrict__ sync, int* __restrict__ hbuf) {
  constexpr bool RING = (MODE < 2);
  const int blk = blockIdx.x;
  const int d = blk & 1;
  const int w = blk >> 1;
  const int tid = threadIdx.x;
  const int lane = tid & 63;
  const int wv = tid >> 6;
  const int nt = wv >> 1;
  const int kh = wv & 1;

  const float* Wih = d ? WihB : WihF;
  const float* Whh = d ? WhhB : WhhF;
  const float* bih = d ? bihB : bihF;
  const float* bhh = d ? bhhB : bhhF;

  const int nn = lane & 15;
  const int quad = lane >> 4;
  const int n32 = nt * 16 + nn;
  const int gg = n32 >> 3;
  const int jj = n32 & 7;
  const int gc = gg * HDIM + w * 8 + jj;

  half8 wihf[8], whhf[8];
#pragma unroll
  for (int kbi = 0; kbi < 8; ++kbi) {
    const int k0 = (kh * 8 + kbi) * 32 + quad * 8;
    const f32x4* pi = (const f32x4*)(Wih + (size_t)gc * HDIM + k0);
    const f32x4* ph = (const f32x4*)(Whh + (size_t)gc * HDIM + k0);
    f32x4 i0 = pi[0], i1 = pi[1], h0 = ph[0], h1 = ph[1];
    half8 a, b;
#pragma unroll
    for (int j = 0; j < 4; ++j) {
      a[j] = (_Float16)i0[j]; a[4 + j] = (_Float16)i1[j];
      b[j] = (_Float16)h0[j]; b[4 + j] = (_Float16)h1[j];
    }
    wihf[kbi] = a; whhf[kbi] = b;
  }
  const float bseed = kh ? 0.f : (bih[gc] + bhh[gc]);

  const int cb = tid >> 3;
  const int cj = tid & 7;
  const int cmt = cb >> 4;
  const int creg = cb & 3;
  const int crow = (cb & 15) >> 2;
  float c = 0.f;

  __shared__ f32x4 part[8][64];

  const int tstep = d ? -1 : 1;
  int tx = d ? (TDIM - 1) : 0;

  for (int s = 0; s < TDIM; ++s, tx += tstep) {
    f32x4 acc0 = {bseed, bseed, bseed, bseed};
    f32x4 acc1 = acc0;

#pragma unroll
    for (int kbi = 0; kbi < 8; ++kbi) {
      const int k0 = (kh * 8 + kbi) * 32 + quad * 8;
      {
        const f32x4* px = (const f32x4*)(x + ((size_t)nn * TDIM + tx) * HDIM + k0);
        f32x4 u0 = px[0], u1 = px[1];
        half8 ax;
#pragma unroll
        for (int j = 0; j < 4; ++j) { ax[j] = (_Float16)u0[j]; ax[4 + j] = (_Float16)u1[j]; }
        acc0 = __builtin_amdgcn_mfma_f32_16x16x32_f16(ax, wihf[kbi], acc0, 0, 0, 0);
      }
      {
        const f32x4* px = (const f32x4*)(x + ((size_t)(16 + nn) * TDIM + tx) * HDIM + k0);
        f32x4 u0 = px[0], u1 = px[1];
        half8 ax;
#pragma unroll
        for (int j = 0; j < 4; ++j) { ax[j] = (_Float16)u0[j]; ax[4 + j] = (_Float16)u1[j]; }
        acc1 = __builtin_amdgcn_mfma_f32_16x16x32_f16(ax, wihf[kbi], acc1, 0, 0, 0);
      }
    }

    if (s > 0) {
      if (MODE == 0) {
        if (wv == 0) {
          const int* pf = sync + (size_t)(d * SLOTS + s) * FLAGN + lane;
          while (__hip_atomic_load(pf, __ATOMIC_RELAXED, __HIP_MEMORY_SCOPE_AGENT) == 0) {}
        }
      } else {
        if (tid == 0) {
          const int* pc = sync + (size_t)(d * SLOTS + s) * CSTRIDE;
          while (__hip_atomic_load(pc, __ATOMIC_RELAXED, __HIP_MEMORY_SCOPE_AGENT) < NWG) {}
        }
      }
      __syncthreads();
    }

    if (RING) {
      const _Float16* hb =
          (const _Float16*)(hbuf + ((size_t)s * 2 + d) * SLICE_INTS);
#pragma unroll
      for (int kbi = 0; kbi < 8; ++kbi) {
        const int k0 = (kh * 8 + kbi) * 32 + quad * 8;
        half8 a0 = *(const half8*)(hb + nn * HDIM + k0);
        acc0 = __builtin_amdgcn_mfma_f32_16x16x32_f16(a0, whhf[kbi], acc0, 0, 0, 0);
        half8 a1 = *(const half8*)(hb + (16 + nn) * HDIM + k0);
        acc1 = __builtin_amdgcn_mfma_f32_16x16x32_f16(a1, whhf[kbi], acc1, 0, 0, 0);
      }
    } else {
      const unsigned long long* hb = (const unsigned long long*)(
          hbuf + ((size_t)(s & 1) * 2 + d) * SLICE_INTS);
#pragma unroll
      for (int kbi = 0; kbi < 8; ++kbi) {
        const int k0 = (kh * 8 + kbi) * 32 + quad * 8;
        {
          const unsigned long long* p = hb + (nn * (HDIM / 4) + (k0 >> 2));
          u64x2 q;
          q[0] = __hip_atomic_load(p, __ATOMIC_RELAXED, __HIP_MEMORY_SCOPE_AGENT);
          q[1] = __hip_atomic_load(p + 1, __ATOMIC_RELAXED, __HIP_MEMORY_SCOPE_AGENT);
          half8 a0 = __builtin_bit_cast(half8, q);
          acc0 = __builtin_amdgcn_mfma_f32_16x16x32_f16(a0, whhf[kbi], acc0, 0, 0, 0);
        }
        {
          const unsigned long long* p = hb + ((16 + nn) * (HDIM / 4) + (k0 >> 2));
          u64x2 q;
          q[0] = __hip_atomic_load(p, __ATOMIC_RELAXED, __HIP_MEMORY_SCOPE_AGENT);
          q[1] = __hip_atomic_load(p + 1, __ATOMIC_RELAXED, __HIP_MEMORY_SCOPE_AGENT);
          half8 a1 = __builtin_bit_cast(half8, q);
          acc1 = __builtin_amdgcn_mfma_f32_16x16x32_f16(a1, whhf[kbi], acc1, 0, 0, 0);
        }
      }
    }

    part[wv * 2 + 0][lane] = acc0;
    part[wv * 2 + 1][lane] = acc1;
    __syncthreads();

    float gv[4];
#pragma unroll
    for (int g4 = 0; g4 < 4; ++g4) {
      const int n32g = g4 * 8 + cj;
      const int ntg = n32g >> 4;
      const int ng = n32g & 15;
      const int lg = (crow << 4) | ng;
      f32x4 p0 = part[(ntg * 2 + 0) * 2 + cmt][lg];
      f32x4 p1 = part[(ntg * 2 + 1) * 2 + cmt][lg];
      gv[g4] = p0[creg] + p1[creg];
    }
    const float ig = sigm(gv[0]);
    const float fg = sigm(gv[1]);
    const float gt = tanh_f(gv[2]);
    const float og = sigm(gv[3]);
    c = fg * c + ig * gt;
    const float h = og * tanh_f(c);

    const float hn = __shfl_xor(h, 1);
    {
      const size_t tdst = RING ? (size_t)(s + 1) : (size_t)((s + 1) & 1);
      int* hw = hbuf + (tdst * 2 + d) * SLICE_INTS;
      if (!(tid & 1)) {
        const unsigned lo = (unsigned)__builtin_bit_cast(unsigned short, (_Float16)h);
        const unsigned hi = (unsigned)__builtin_bit_cast(unsigned short, (_Float16)hn);
        const int packed = (int)(lo | (hi << 16));
        __hip_atomic_store(hw + cb * (HDIM / 2) + ((w * 8 + cj) >> 1), packed,
                           __ATOMIC_RELAXED, __HIP_MEMORY_SCOPE_AGENT);
      }
    }

    __syncthreads();
    if (tid == 0) {
      if (MODE == 0) {
        __hip_atomic_store(sync + (size_t)(d * SLOTS + s + 1) * FLAGN + w, 1,
                           __ATOMIC_RELAXED, __HIP_MEMORY_SCOPE_AGENT);
      } else {
        __hip_atomic_fetch_add(sync + (size_t)(d * SLOTS + s + 1) * CSTRIDE, 1,
                               __ATOMIC_RELAXED, __HIP_MEMORY_SCOPE_AGENT);
      }
    }

    out[((size_t)cb * TDIM + tx) * (2 * HDIM) + d * HDIM + w * 8 + cj] = h;
  }
}

extern "C" void kernel_launch(void* const* d_in, const int* in_sizes, int n_in,
                              void* d_out, int out_size, void* d_ws, size_t ws_size,
                              hipStream_t stream) {
  const float* x    = (const float*)d_in[0];
  const float* WihF = (const float*)d_in[1];
  const float* WhhF = (const float*)d_in[2];
  const float* bihF = (const float*)d_in[3];
  const float* bhhF = (const float*)d_in[4];
  const float* WihB = (const float*)d_in[5];
  const float* WhhB = (const float*)d_in[6];
  const float* bihB = (const float*)d_in[7];
  const float* bhhB = (const float*)d_in[8];
  float* out = (float*)d_out;

  int* sync = (int*)d_ws;
  const size_t sync_bytes = (size_t)SYNC_INTS * 4;            // ~263 KB
  const size_t flag_bytes = (size_t)FLAG_INTS * 4;            // fallback layout
  const size_t cnt_bytes  = (size_t)2 * SLOTS * CSTRIDE * 4;
  const size_t ring_bytes = (size_t)SLOTS * 2 * SLICE_INTS * 4;   // 33.6 MB
  const size_t xg_bytes   = (size_t)2 * 512 * 32 * 2048 * 2;      // 128 MiB
  const size_t new_req = sync_bytes + ring_bytes + xg_bytes;      // ~160.3 MiB

  if (ws_size >= new_req) {
    int* hbuf = (int*)((char*)d_ws + sync_bytes);
    _Float16* xg = (_Float16*)((char*)d_ws + sync_bytes + ring_bytes);
    hipLaunchKernelGGL(init_ws_kernel, dim3(256), dim3(NTHR), 0, stream,
                       sync, hbuf, (int)SYNC_INTS);
    hipLaunchKernelGGL(xg_gemm, dim3(4096), dim3(NTHR), 0, stream,
                       x, WihF, bihF, bhhF, WihB, bihB, bhhB, xg);
    hipLaunchKernelGGL(lstm_rec, dim3(GRID_REC), dim3(NTHR), 0, stream,
                       WhhF, WhhB, out, sync, hbuf, xg);
    return;
  }

  // fallback tiers (R5)
  const size_t ringF_bytes = flag_bytes + ring_bytes;
  const size_t ringC_bytes = cnt_bytes + ring_bytes;
  const int mode = (ws_size >= ringF_bytes) ? 0 : (ws_size >= ringC_bytes ? 1 : 2);
  int* hbuf = (int*)((char*)d_ws + (mode == 0 ? flag_bytes : cnt_bytes));
  const int nzero = (mode == 0) ? FLAG_INTS : 2 * SLOTS * CSTRIDE;

  hipLaunchKernelGGL(init_ws_kernel, dim3(256), dim3(NTHR), 0, stream,
                     sync, hbuf, nzero);
  if (mode == 0) {
    hipLaunchKernelGGL((lstm_kernel<0>), dim3(2 * NWG), dim3(NTHR), 0, stream,
                       x, WihF, WhhF, bihF, bhhF, WihB, WhhB, bihB, bhhB,
                       out, sync, hbuf);
  } else if (mode == 1) {
    hipLaunchKernelGGL((lstm_kernel<1>), dim3(2 * NWG), dim3(NTHR), 0, stream,
                       x, WihF, WhhF, bihF, bhhF, WihB, WhhB, bihB, bhhB,
                       out, sync, hbuf);
  } else {
    hipLaunchKernelGGL((lstm_kernel<2>), dim3(2 * NWG), dim3(NTHR), 0, stream,
                       x, WihF, WhhF, bihF, bhhF, WihB, WhhB, bihB, bhhB,
                       out, sync, hbuf);
  }
}